// Round 5
// baseline (1727.628 us; speedup 1.0000x reference)
//
#include <hip/hip_runtime.h>
#include <math.h>

// Problem constants (match reference).
constexpr int B_ = 4, S_ = 4096, D_ = 1024, FF_ = 2048, V_ = 512;
constexpr int L_ = 2, OD_ = 64, GD_ = 8, PD_ = 72;
constexpr float SCALE_ = 0.03125f;   // 1/sqrt(1024)

using bf16x8 = __attribute__((ext_vector_type(8))) __bf16;
using bf16x4 = __attribute__((ext_vector_type(4))) __bf16;
using f32x4  = __attribute__((ext_vector_type(4))) float;

// ---------------- helpers ----------------

__device__ __forceinline__ float blockReduceSum(float v, float* sh) {
    #pragma unroll
    for (int off = 32; off > 0; off >>= 1) v += __shfl_down(v, off, 64);
    int t = threadIdx.x;
    if ((t & 63) == 0) sh[t >> 6] = v;
    __syncthreads();
    float r = sh[0] + sh[1] + sh[2] + sh[3];
    __syncthreads();
    return r;
}

__device__ __forceinline__ float blockReduceMax(float v, float* sh) {
    #pragma unroll
    for (int off = 32; off > 0; off >>= 1) v = fmaxf(v, __shfl_down(v, off, 64));
    int t = threadIdx.x;
    if ((t & 63) == 0) sh[t >> 6] = v;
    __syncthreads();
    float r = fmaxf(fmaxf(sh[0], sh[1]), fmaxf(sh[2], sh[3]));
    __syncthreads();
    return r;
}

// async 16B global->LDS (dest must be wave-uniform; HW adds lane*16)
__device__ __forceinline__ void gload_lds16(const void* g, void* lds) {
    __builtin_amdgcn_global_load_lds(
        (const __attribute__((address_space(1))) unsigned int*)g,
        (__attribute__((address_space(3))) unsigned int*)lds,
        16, 0, 0);
}

// ---------------- embedding side ----------------

__global__ __launch_bounds__(256) void proj_kernel(
    const int* __restrict__ occ, const int* __restrict__ gen,
    const float* __restrict__ oe, const float* __restrict__ ge,
    const float* __restrict__ W, const float* __restrict__ pb,
    float* __restrict__ out)
{
    __shared__ float agg[PD_];
    int b = blockIdx.x, t = threadIdx.x;
    if (t < OD_)       agg[t] = oe[occ[b] * OD_ + t];
    else if (t < PD_)  agg[t] = ge[gen[b] * GD_ + (t - OD_)];
    __syncthreads();
    float4 acc = reinterpret_cast<const float4*>(pb)[t];
    #pragma unroll 8
    for (int k = 0; k < PD_; ++k) {
        float a = agg[k];
        float4 w = reinterpret_cast<const float4*>(W + k * D_)[t];
        acc.x = fmaf(a, w.x, acc.x); acc.y = fmaf(a, w.y, acc.y);
        acc.z = fmaf(a, w.z, acc.z); acc.w = fmaf(a, w.w, acc.w);
    }
    reinterpret_cast<float4*>(out + b * D_)[t] = acc;
}

__global__ __launch_bounds__(256) void embed_kernel(
    const int* __restrict__ ids, const float* __restrict__ tok,
    const float* __restrict__ pos, const float* __restrict__ pr,
    float* __restrict__ x)
{
    int row = blockIdx.x, t = threadIdx.x;
    int b = row >> 12;                 // S = 4096
    int s = row & (S_ - 1);
    int tk = ids[row];
    float4 a = reinterpret_cast<const float4*>(tok + (size_t)tk * D_)[t];
    float4 p = reinterpret_cast<const float4*>(pos + (size_t)s * D_)[t];
    float4 q = reinterpret_cast<const float4*>(pr + (size_t)b * D_)[t];
    a.x += p.x + q.x; a.y += p.y + q.y; a.z += p.z + q.z; a.w += p.w + q.w;
    reinterpret_cast<float4*>(x + (size_t)row * D_)[t] = a;
}

// ---------------- layernorm (fp32 in, bf16 out) ----------------

__global__ __launch_bounds__(256) void ln_kernel(
    const float* __restrict__ x, __bf16* __restrict__ nb,
    const float* __restrict__ w, const float* __restrict__ b)
{
    __shared__ float sh[4];
    int row = blockIdx.x, t = threadIdx.x;
    float4 v = reinterpret_cast<const float4*>(x + (size_t)row * D_)[t];
    float s = v.x + v.y + v.z + v.w;
    float q = v.x * v.x + v.y * v.y + v.z * v.z + v.w * v.w;
    float ssum = blockReduceSum(s, sh);
    float qsum = blockReduceSum(q, sh);
    float mean = ssum * (1.0f / D_);
    float var  = qsum * (1.0f / D_) - mean * mean;
    float rstd = rsqrtf(var + 1e-5f);
    float4 w4 = reinterpret_cast<const float4*>(w)[t];
    float4 b4 = reinterpret_cast<const float4*>(b)[t];
    bf16x4 o;
    o[0] = (__bf16)((v.x - mean) * rstd * w4.x + b4.x);
    o[1] = (__bf16)((v.y - mean) * rstd * w4.y + b4.y);
    o[2] = (__bf16)((v.z - mean) * rstd * w4.z + b4.z);
    o[3] = (__bf16)((v.w - mean) * rstd * w4.w + b4.w);
    reinterpret_cast<bf16x4*>(nb + (size_t)row * D_)[t] = o;
}

// ---------------- in-place row softmax on bf16 scores (scale+mask folded) ------

__global__ __launch_bounds__(256) void softmax_b16(
    __bf16* __restrict__ sc, const float* __restrict__ mask)
{
    __shared__ float sh[4];
    int row = blockIdx.x, t = threadIdx.x;
    __bf16* p = sc + (size_t)row * S_;
    float v[16];
    float mx = -1e30f;
    #pragma unroll
    for (int j = 0; j < 2; ++j) {
        bf16x8 s8 = reinterpret_cast<const bf16x8*>(p)[j * 256 + t];
        int e2 = (j * 256 + t) * 2;
        float4 ma = reinterpret_cast<const float4*>(mask)[e2];
        float4 mb = reinterpret_cast<const float4*>(mask)[e2 + 1];
        float mf[8] = {ma.x, ma.y, ma.z, ma.w, mb.x, mb.y, mb.z, mb.w};
        #pragma unroll
        for (int i = 0; i < 8; ++i) {
            float s = (float)s8[i] * SCALE_ + (1.0f - mf[i]) * (-1e9f);
            v[j * 8 + i] = s;
            mx = fmaxf(mx, s);
        }
    }
    float gm = blockReduceMax(mx, sh);
    float sum = 0.0f;
    #pragma unroll
    for (int i = 0; i < 16; ++i) { v[i] = __expf(v[i] - gm); sum += v[i]; }
    float gs = blockReduceSum(sum, sh);
    float inv = 1.0f / gs;
    #pragma unroll
    for (int j = 0; j < 2; ++j) {
        bf16x8 o;
        #pragma unroll
        for (int i = 0; i < 8; ++i) o[i] = (__bf16)(v[j * 8 + i] * inv);
        reinterpret_cast<bf16x8*>(p)[j * 256 + t] = o;
    }
}

// ---------------- transpose-cast kernels ----------------

template<int SPLIT>
__global__ __launch_bounds__(256) void tcast_f32(
    const float* __restrict__ in, __bf16* __restrict__ hi,
    __bf16* __restrict__ lo, int R, int C)
{
    __shared__ float tile[32][33];
    int c0 = blockIdx.x * 32, r0 = blockIdx.y * 32;
    int tx = threadIdx.x & 31, ty = threadIdx.x >> 5;
    #pragma unroll
    for (int i = 0; i < 32; i += 8)
        tile[ty + i][tx] = in[(size_t)(r0 + ty + i) * C + c0 + tx];
    __syncthreads();
    #pragma unroll
    for (int i = 0; i < 32; i += 8) {
        float v = tile[tx][ty + i];
        size_t o = (size_t)(c0 + ty + i) * R + r0 + tx;
        __bf16 h = (__bf16)v;
        hi[o] = h;
        if (SPLIT) lo[o] = (__bf16)(v - (float)h);
    }
}

__global__ __launch_bounds__(256) void tcast_b16(
    const __bf16* __restrict__ in, __bf16* __restrict__ out, int R, int C)
{
    __shared__ __bf16 tile[32][33];
    const __bf16* ib = in  + (size_t)blockIdx.z * R * C;
    __bf16*       ob = out + (size_t)blockIdx.z * R * C;
    int c0 = blockIdx.x * 32, r0 = blockIdx.y * 32;
    int tx = threadIdx.x & 31, ty = threadIdx.x >> 5;
    #pragma unroll
    for (int i = 0; i < 32; i += 8)
        tile[ty + i][tx] = ib[(size_t)(r0 + ty + i) * C + c0 + tx];
    __syncthreads();
    #pragma unroll
    for (int i = 0; i < 32; i += 8)
        ob[(size_t)(c0 + ty + i) * R + r0 + tx] = tile[tx][ty + i];
}

__global__ __launch_bounds__(256) void splitx_kernel(
    const float* __restrict__ x, __bf16* __restrict__ hi,
    __bf16* __restrict__ lo, long n4)
{
    long i = (long)blockIdx.x * 256 + threadIdx.x;
    if (i >= n4) return;
    float4 v = reinterpret_cast<const float4*>(x)[i];
    bf16x4 h, lw;
    h[0] = (__bf16)v.x; h[1] = (__bf16)v.y; h[2] = (__bf16)v.z; h[3] = (__bf16)v.w;
    lw[0] = (__bf16)(v.x - (float)h[0]); lw[1] = (__bf16)(v.y - (float)h[1]);
    lw[2] = (__bf16)(v.z - (float)h[2]); lw[3] = (__bf16)(v.w - (float)h[3]);
    reinterpret_cast<bf16x4*>(hi)[i] = h;
    reinterpret_cast<bf16x4*>(lo)[i] = lw;
}

// ---------------- deep-pipelined MFMA GEMM (NT): C = A[M][K] @ BT[N][K]^T -------
// 256x256 tile, BK=32, 8 waves (2Mx4N), 512 threads.
// LDS: 4-slot ring per operand (4 x 16KB x 2 = 128KB). Prefetch distance 3 slots;
// counted s_waitcnt vmcnt(12) (never 0 in steady state) lets 3 K-slots of loads
// stay in flight across barriers (T3+T4). Raw s_barrier (no implicit drain).
// Slot-ring safety: stage(t+3) targets slot (t-1)&3, protected by the barrier at
// the END of iteration t-1 (all ds_reads of that slot serviced before any wave
// passes it). vmcnt(12) + barrier guarantees slot t fully landed before reads.
// T2: 16B-chunk XOR swizzle (chunk ^= (row>>1)&3) via pre-swizzled GLOBAL source
// (linear gload_lds dest) + swizzled ds_read -> 2-way (free) bank access.
// T5: setprio(1) around the 32-MFMA cluster.
// T1: XCD-aware bijective block swizzle over linearized grid (nwg % 8 == 0).

template<int HAS_BIAS, int HAS_RES, int RELU, int OUT_BF16, int ACCUM>
__global__ __launch_bounds__(512, 2) void mgemm3(
    const __bf16* __restrict__ A, const __bf16* __restrict__ Bm,
    void* __restrict__ Cv, const float* __restrict__ bias,
    const float* __restrict__ res,
    int M, int N, int K, int lda, int ldb, int nbx,
    size_t sA, size_t sB, size_t sC)
{
    __shared__ __bf16 As[4][8192];   // slot: 256 rows x 32 k
    __shared__ __bf16 Bs[4][8192];
    const int t = threadIdx.x;
    const int w = t >> 6, l = t & 63;
    const int lr = l & 15, lk = l >> 4;
    // T1: XCD swizzle (all grids here are multiples of 8)
    const int nwg = gridDim.x;
    const int o = blockIdx.x;
    const int sid = (o & 7) * (nwg >> 3) + (o >> 3);
    const int bx = sid % nbx, by = sid / nbx;
    const int gm0 = by * 256, gn0 = bx * 256;
    const int wr = w >> 2, wc = w & 3;          // wave -> 128x64 output sub-tile
    const int z = blockIdx.y;
    A  += (size_t)z * sA;
    Bm += (size_t)z * sB;

    // staging geometry: per thread 2 gloads/operand/slot; wave w instr j covers
    // LDS rows [(w*2+j)*16, +16) linearly; source chunk pre-swizzled.
    const int srow16 = w * 2;
    const int lrow   = l >> 2;                    // row within 16-row block
    const int schunk = (l & 3) ^ ((l >> 3) & 3);  // swizzled source 16B chunk

    auto stage = [&](int kt) {
        const int slot = kt & 3;
        const int kb = kt << 5;
        #pragma unroll
        for (int j = 0; j < 2; ++j) {
            int row = (srow16 + j) * 16 + lrow;
            gload_lds16(A + (size_t)(gm0 + row) * lda + kb + schunk * 8,
                        (char*)(&As[slot][0]) + (srow16 + j) * 1024);
        }
        #pragma unroll
        for (int j = 0; j < 2; ++j) {
            int row = (srow16 + j) * 16 + lrow;
            gload_lds16(Bm + (size_t)(gn0 + row) * ldb + kb + schunk * 8,
                        (char*)(&Bs[slot][0]) + (srow16 + j) * 1024);
        }
    };

    f32x4 acc[8][4] = {};
    const int nkt = K >> 5;
    stage(0); stage(1); stage(2);

    const int swz = (lk ^ ((lr >> 1) & 3)) * 8;   // swizzled read chunk (elements)
    for (int kt = 0; kt < nkt; ++kt) {
        const int slot = kt & 3;
        if (kt + 3 < nkt) {
            stage(kt + 3);
            asm volatile("s_waitcnt vmcnt(12)" ::: "memory");
        } else {
            int rem = nkt - 1 - kt;
            if (rem == 2)      asm volatile("s_waitcnt vmcnt(8)" ::: "memory");
            else if (rem == 1) asm volatile("s_waitcnt vmcnt(4)" ::: "memory");
            else               asm volatile("s_waitcnt vmcnt(0)" ::: "memory");
        }
        __builtin_amdgcn_s_barrier();     // slot `kt` fully in LDS for all waves
        bf16x8 a[8], b[4];
        #pragma unroll
        for (int mi = 0; mi < 8; ++mi) {
            int row = wr * 128 + mi * 16 + lr;
            a[mi] = *reinterpret_cast<const bf16x8*>(&As[slot][row * 32 + swz]);
        }
        #pragma unroll
        for (int nj = 0; nj < 4; ++nj) {
            int row = wc * 64 + nj * 16 + lr;
            b[nj] = *reinterpret_cast<const bf16x8*>(&Bs[slot][row * 32 + swz]);
        }
        __builtin_amdgcn_s_setprio(1);
        #pragma unroll
        for (int mi = 0; mi < 8; ++mi)
            #pragma unroll
            for (int nj = 0; nj < 4; ++nj)
                acc[mi][nj] = __builtin_amdgcn_mfma_f32_16x16x32_bf16(
                    a[mi], b[nj], acc[mi][nj], 0, 0, 0);
        __builtin_amdgcn_s_setprio(0);
        __builtin_amdgcn_s_barrier();     // protect slot before ring reuse
    }

    float*  Cf = (float*)Cv  + (size_t)z * sC;
    __bf16* Cb = (__bf16*)Cv + (size_t)z * sC;
    const float* rp = HAS_RES ? (res + (size_t)z * sC) : nullptr;
    #pragma unroll
    for (int mi = 0; mi < 8; ++mi) {
        int rbase = gm0 + wr * 128 + mi * 16 + lk * 4;
        #pragma unroll
        for (int nj = 0; nj < 4; ++nj) {
            int col = gn0 + wc * 64 + nj * 16 + lr;
            float bv = HAS_BIAS ? bias[col] : 0.0f;
            #pragma unroll
            for (int r = 0; r < 4; ++r) {
                size_t oo = (size_t)(rbase + r) * N + col;
                float val = acc[mi][nj][r] + bv;
                if (RELU) val = fmaxf(val, 0.0f);
                if (HAS_RES) val += rp[oo];
                if (OUT_BF16)    Cb[oo] = (__bf16)val;
                else if (ACCUM)  Cf[oo] += val;
                else             Cf[oo] = val;
            }
        }
    }
}

// ---------------- launch ----------------

extern "C" void kernel_launch(void* const* d_in, const int* in_sizes, int n_in,
                              void* d_out, int out_size, void* d_ws, size_t ws_size,
                              hipStream_t stream)
{
    (void)in_sizes; (void)n_in; (void)out_size; (void)ws_size;
    const int*   ids  = (const int*)d_in[0];
    const int*   occ  = (const int*)d_in[1];
    const int*   gen  = (const int*)d_in[2];
    const float* mask = (const float*)d_in[3];
    const float* tok  = (const float*)d_in[4];
    const float* pos  = (const float*)d_in[5];
    const float* oe   = (const float*)d_in[6];
    const float* ge   = (const float*)d_in[7];
    const float* pW   = (const float*)d_in[8];
    const float* pb   = (const float*)d_in[9];
    const float* lnw  = (const float*)d_in[10];
    const float* lnb  = (const float*)d_in[11];
    const float* w1   = (const float*)d_in[12];
    const float* b1   = (const float*)d_in[13];
    const float* w2   = (const float*)d_in[14];
    const float* b2   = (const float*)d_in[15];
    const float* oW   = (const float*)d_in[16];
    const float* ob   = (const float*)d_in[17];
    float* out = (float*)d_out;

    const size_t SD = (size_t)S_ * D_;
    const size_t SS = (size_t)S_ * S_;
    // Workspace total ~210 MB (proven safe in R4; R3's 274 MB crashed).
    char* wp = (char*)d_ws;
    float* x    = (float*)wp;  wp += (size_t)B_ * SD * 4;      // fp32 residual (64MB)
    float* pr   = (float*)wp;  wp += (size_t)B_ * D_ * 4;      // proj rows
    __bf16* n_bf  = (__bf16*)wp; wp += (size_t)B_ * SD * 2;    // LN out [B*S][D] (32MB)
    __bf16* n_bfT = (__bf16*)wp; wp += (size_t)B_ * SD * 2;    // [B][D][S] (32MB)
    __bf16* big   = (__bf16*)wp; wp += 2 * SS * 2;             // scores pair | FFN h (64MB)
    __bf16* w1t   = (__bf16*)wp; wp += (size_t)L_ * FF_ * D_ * 2;  // 8MB
    __bf16* w2t   = (__bf16*)wp; wp += (size_t)L_ * D_ * FF_ * 2;  // 8MB
    __bf16* owh   = (__bf16*)wp; wp += (size_t)V_ * D_ * 2;        // 1MB
    __bf16* owl   = (__bf16*)wp; wp += (size_t)V_ * D_ * 2;        // 1MB
    __bf16* x_hi  = n_bf;    // aliased: n_bf dead after final FFN1
    __bf16* x_lo  = n_bfT;   // aliased: n_bfT dead after final PV

    proj_kernel<<<B_, 256, 0, stream>>>(occ, gen, oe, ge, pW, pb, pr);
    embed_kernel<<<B_ * S_, 256, 0, stream>>>(ids, tok, pos, pr, x);

    for (int l = 0; l < L_; ++l) {
        tcast_f32<0><<<dim3(FF_ / 32, D_ / 32), 256, 0, stream>>>(
            w1 + (size_t)l * D_ * FF_, w1t + (size_t)l * FF_ * D_, nullptr, D_, FF_);
        tcast_f32<0><<<dim3(D_ / 32, FF_ / 32), 256, 0, stream>>>(
            w2 + (size_t)l * FF_ * D_, w2t + (size_t)l * D_ * FF_, nullptr, FF_, D_);
    }
    tcast_f32<1><<<dim3(V_ / 32, D_ / 32), 256, 0, stream>>>(oW, owh, owl, D_, V_);

    for (int l = 0; l < L_; ++l) {
        const float* w  = lnw + l * D_;
        const float* bb = lnb + l * D_;
        ln_kernel<<<B_ * S_, 256, 0, stream>>>(x, n_bf, w, bb);
        tcast_b16<<<dim3(D_ / 32, S_ / 32, B_), 256, 0, stream>>>(n_bf, n_bfT, S_, D_);
        for (int p = 0; p < 2; ++p) {            // batch pairs
            for (int q = 0; q < 2; ++q) {
                int b = 2 * p + q;
                // scores (bf16) = n_b @ n_b^T  (scale folded into softmax)
                mgemm3<0, 0, 0, 1, 0><<<dim3((S_/256)*(S_/256), 1), 512, 0, stream>>>(
                    n_bf + b * SD, n_bf + b * SD, big + q * SS, nullptr, nullptr,
                    S_, S_, D_, D_, D_, S_ / 256, 0, 0, 0);
                softmax_b16<<<S_, 256, 0, stream>>>(big + q * SS, mask + (size_t)b * S_);
            }
            // x += probs @ n  for both batches of the pair (z = 2)
            mgemm3<0, 1, 0, 0, 0><<<dim3((D_/256)*(S_/256), 2), 512, 0, stream>>>(
                big, n_bfT + (size_t)(2 * p) * SD, x + (size_t)(2 * p) * SD,
                nullptr, x + (size_t)(2 * p) * SD,
                S_, D_, S_, S_, S_, D_ / 256, SS, SD, SD);
        }
        ln_kernel<<<B_ * S_, 256, 0, stream>>>(x, n_bf, w, bb);
        // h = relu(na @ W1 + b1), all batches, bf16 out into big
        mgemm3<1, 0, 1, 1, 0><<<dim3((FF_/256)*((B_*S_)/256), 1), 512, 0, stream>>>(
            n_bf, w1t + (size_t)l * FF_ * D_, big, b1 + l * FF_, nullptr,
            B_ * S_, FF_, D_, D_, D_, FF_ / 256, 0, 0, 0);
        // x += h @ W2 + b2
        mgemm3<1, 1, 0, 0, 0><<<dim3((D_/256)*((B_*S_)/256), 1), 512, 0, stream>>>(
            big, w2t + (size_t)l * D_ * FF_, x, b2 + l * D_, x,
            B_ * S_, D_, FF_, FF_, FF_, D_ / 256, 0, 0, 0);
    }

    // out = x @ out_W + out_b, split-bf16 (hi*hi + hi*lo + lo*hi)
    splitx_kernel<<<(int)((B_ * SD / 4 + 255) / 256), 256, 0, stream>>>(
        x, x_hi, x_lo, (long)(B_ * SD / 4));
    mgemm3<1, 0, 0, 0, 0><<<dim3((V_/256)*((B_*S_)/256), 1), 512, 0, stream>>>(
        x_hi, owh, out, ob, nullptr, B_ * S_, V_, D_, D_, D_, V_ / 256, 0, 0, 0);
    mgemm3<0, 0, 0, 0, 1><<<dim3((V_/256)*((B_*S_)/256), 1), 512, 0, stream>>>(
        x_hi, owl, out, nullptr, nullptr, B_ * S_, V_, D_, D_, D_, V_ / 256, 0, 0, 0);
    mgemm3<0, 0, 0, 0, 1><<<dim3((V_/256)*((B_*S_)/256), 1), 512, 0, stream>>>(
        x_lo, owh, out, nullptr, nullptr, B_ * S_, V_, D_, D_, D_, V_ / 256, 0, 0, 0);
}

// Round 6
// 1292.621 us; speedup vs baseline: 1.3365x; 1.3365x over previous
//
#include <hip/hip_runtime.h>
#include <math.h>

// Problem constants (match reference).
constexpr int B_ = 4, S_ = 4096, D_ = 1024, FF_ = 2048, V_ = 512;
constexpr int L_ = 2, OD_ = 64, GD_ = 8, PD_ = 72;
constexpr float SCALE_ = 0.03125f;   // 1/sqrt(1024)

using bf16x8 = __attribute__((ext_vector_type(8))) __bf16;
using bf16x4 = __attribute__((ext_vector_type(4))) __bf16;
using f32x4  = __attribute__((ext_vector_type(4))) float;

// ---------------- helpers ----------------

__device__ __forceinline__ float blockReduceSum(float v, float* sh) {
    #pragma unroll
    for (int off = 32; off > 0; off >>= 1) v += __shfl_down(v, off, 64);
    int t = threadIdx.x;
    if ((t & 63) == 0) sh[t >> 6] = v;
    __syncthreads();
    float r = sh[0] + sh[1] + sh[2] + sh[3];
    __syncthreads();
    return r;
}

__device__ __forceinline__ float blockReduceMax(float v, float* sh) {
    #pragma unroll
    for (int off = 32; off > 0; off >>= 1) v = fmaxf(v, __shfl_down(v, off, 64));
    int t = threadIdx.x;
    if ((t & 63) == 0) sh[t >> 6] = v;
    __syncthreads();
    float r = fmaxf(fmaxf(sh[0], sh[1]), fmaxf(sh[2], sh[3]));
    __syncthreads();
    return r;
}

// async 16B global->LDS (dest must be wave-uniform; HW adds lane*16)
__device__ __forceinline__ void gload_lds16(const void* g, void* lds) {
    __builtin_amdgcn_global_load_lds(
        (const __attribute__((address_space(1))) unsigned int*)g,
        (__attribute__((address_space(3))) unsigned int*)lds,
        16, 0, 0);
}

// ---------------- embedding side ----------------

__global__ __launch_bounds__(256) void proj_kernel(
    const int* __restrict__ occ, const int* __restrict__ gen,
    const float* __restrict__ oe, const float* __restrict__ ge,
    const float* __restrict__ W, const float* __restrict__ pb,
    float* __restrict__ out)
{
    __shared__ float agg[PD_];
    int b = blockIdx.x, t = threadIdx.x;
    if (t < OD_)       agg[t] = oe[occ[b] * OD_ + t];
    else if (t < PD_)  agg[t] = ge[gen[b] * GD_ + (t - OD_)];
    __syncthreads();
    float4 acc = reinterpret_cast<const float4*>(pb)[t];
    #pragma unroll 8
    for (int k = 0; k < PD_; ++k) {
        float a = agg[k];
        float4 w = reinterpret_cast<const float4*>(W + k * D_)[t];
        acc.x = fmaf(a, w.x, acc.x); acc.y = fmaf(a, w.y, acc.y);
        acc.z = fmaf(a, w.z, acc.z); acc.w = fmaf(a, w.w, acc.w);
    }
    reinterpret_cast<float4*>(out + b * D_)[t] = acc;
}

__global__ __launch_bounds__(256) void embed_kernel(
    const int* __restrict__ ids, const float* __restrict__ tok,
    const float* __restrict__ pos, const float* __restrict__ pr,
    float* __restrict__ x)
{
    int row = blockIdx.x, t = threadIdx.x;
    int b = row >> 12;                 // S = 4096
    int s = row & (S_ - 1);
    int tk = ids[row];
    float4 a = reinterpret_cast<const float4*>(tok + (size_t)tk * D_)[t];
    float4 p = reinterpret_cast<const float4*>(pos + (size_t)s * D_)[t];
    float4 q = reinterpret_cast<const float4*>(pr + (size_t)b * D_)[t];
    a.x += p.x + q.x; a.y += p.y + q.y; a.z += p.z + q.z; a.w += p.w + q.w;
    reinterpret_cast<float4*>(x + (size_t)row * D_)[t] = a;
}

// ---------------- layernorm (fp32 in, bf16 out) ----------------

__global__ __launch_bounds__(256) void ln_kernel(
    const float* __restrict__ x, __bf16* __restrict__ nb,
    const float* __restrict__ w, const float* __restrict__ b)
{
    __shared__ float sh[4];
    int row = blockIdx.x, t = threadIdx.x;
    float4 v = reinterpret_cast<const float4*>(x + (size_t)row * D_)[t];
    float s = v.x + v.y + v.z + v.w;
    float q = v.x * v.x + v.y * v.y + v.z * v.z + v.w * v.w;
    float ssum = blockReduceSum(s, sh);
    float qsum = blockReduceSum(q, sh);
    float mean = ssum * (1.0f / D_);
    float var  = qsum * (1.0f / D_) - mean * mean;
    float rstd = rsqrtf(var + 1e-5f);
    float4 w4 = reinterpret_cast<const float4*>(w)[t];
    float4 b4 = reinterpret_cast<const float4*>(b)[t];
    bf16x4 o;
    o[0] = (__bf16)((v.x - mean) * rstd * w4.x + b4.x);
    o[1] = (__bf16)((v.y - mean) * rstd * w4.y + b4.y);
    o[2] = (__bf16)((v.z - mean) * rstd * w4.z + b4.z);
    o[3] = (__bf16)((v.w - mean) * rstd * w4.w + b4.w);
    reinterpret_cast<bf16x4*>(nb + (size_t)row * D_)[t] = o;
}

// ---------------- in-place row softmax on bf16 scores (scale+mask folded) ------

__global__ __launch_bounds__(256) void softmax_b16(
    __bf16* __restrict__ sc, const float* __restrict__ mask)
{
    __shared__ float sh[4];
    int row = blockIdx.x, t = threadIdx.x;
    __bf16* p = sc + (size_t)row * S_;
    float v[16];
    float mx = -1e30f;
    #pragma unroll
    for (int j = 0; j < 2; ++j) {
        bf16x8 s8 = reinterpret_cast<const bf16x8*>(p)[j * 256 + t];
        int e2 = (j * 256 + t) * 2;
        float4 ma = reinterpret_cast<const float4*>(mask)[e2];
        float4 mb = reinterpret_cast<const float4*>(mask)[e2 + 1];
        float mf[8] = {ma.x, ma.y, ma.z, ma.w, mb.x, mb.y, mb.z, mb.w};
        #pragma unroll
        for (int i = 0; i < 8; ++i) {
            float s = (float)s8[i] * SCALE_ + (1.0f - mf[i]) * (-1e9f);
            v[j * 8 + i] = s;
            mx = fmaxf(mx, s);
        }
    }
    float gm = blockReduceMax(mx, sh);
    float sum = 0.0f;
    #pragma unroll
    for (int i = 0; i < 16; ++i) { v[i] = __expf(v[i] - gm); sum += v[i]; }
    float gs = blockReduceSum(sum, sh);
    float inv = 1.0f / gs;
    #pragma unroll
    for (int j = 0; j < 2; ++j) {
        bf16x8 o;
        #pragma unroll
        for (int i = 0; i < 8; ++i) o[i] = (__bf16)(v[j * 8 + i] * inv);
        reinterpret_cast<bf16x8*>(p)[j * 256 + t] = o;
    }
}

// ---------------- transpose-cast kernels ----------------

template<int SPLIT>
__global__ __launch_bounds__(256) void tcast_f32(
    const float* __restrict__ in, __bf16* __restrict__ hi,
    __bf16* __restrict__ lo, int R, int C)
{
    __shared__ float tile[32][33];
    int c0 = blockIdx.x * 32, r0 = blockIdx.y * 32;
    int tx = threadIdx.x & 31, ty = threadIdx.x >> 5;
    #pragma unroll
    for (int i = 0; i < 32; i += 8)
        tile[ty + i][tx] = in[(size_t)(r0 + ty + i) * C + c0 + tx];
    __syncthreads();
    #pragma unroll
    for (int i = 0; i < 32; i += 8) {
        float v = tile[tx][ty + i];
        size_t o = (size_t)(c0 + ty + i) * R + r0 + tx;
        __bf16 h = (__bf16)v;
        hi[o] = h;
        if (SPLIT) lo[o] = (__bf16)(v - (float)h);
    }
}

__global__ __launch_bounds__(256) void tcast_b16(
    const __bf16* __restrict__ in, __bf16* __restrict__ out, int R, int C)
{
    __shared__ __bf16 tile[32][33];
    const __bf16* ib = in  + (size_t)blockIdx.z * R * C;
    __bf16*       ob = out + (size_t)blockIdx.z * R * C;
    int c0 = blockIdx.x * 32, r0 = blockIdx.y * 32;
    int tx = threadIdx.x & 31, ty = threadIdx.x >> 5;
    #pragma unroll
    for (int i = 0; i < 32; i += 8)
        tile[ty + i][tx] = ib[(size_t)(r0 + ty + i) * C + c0 + tx];
    __syncthreads();
    #pragma unroll
    for (int i = 0; i < 32; i += 8)
        ob[(size_t)(c0 + ty + i) * R + r0 + tx] = tile[tx][ty + i];
}

__global__ __launch_bounds__(256) void splitx_kernel(
    const float* __restrict__ x, __bf16* __restrict__ hi,
    __bf16* __restrict__ lo, long n4)
{
    long i = (long)blockIdx.x * 256 + threadIdx.x;
    if (i >= n4) return;
    float4 v = reinterpret_cast<const float4*>(x)[i];
    bf16x4 h, lw;
    h[0] = (__bf16)v.x; h[1] = (__bf16)v.y; h[2] = (__bf16)v.z; h[3] = (__bf16)v.w;
    lw[0] = (__bf16)(v.x - (float)h[0]); lw[1] = (__bf16)(v.y - (float)h[1]);
    lw[2] = (__bf16)(v.z - (float)h[2]); lw[3] = (__bf16)(v.w - (float)h[3]);
    reinterpret_cast<bf16x4*>(hi)[i] = h;
    reinterpret_cast<bf16x4*>(lo)[i] = lw;
}

// ---------------- deep-pipelined MFMA GEMM (NT): C = A[M][K] @ BT[N][K]^T -------
// 256xBN tile (BN=256 or 128), BK=32, 8 waves, 512 threads.
// 4-slot LDS ring, prefetch distance 3, counted vmcnt (steady-state never 0).
// ALL slot indices are compile-time literals (inner 4-iteration loop is fully
// unrolled) so the backend can disambiguate outstanding global_load_lds writes
// from ds_reads per-slot instead of conservatively draining (R5 failure theory).
// Per iteration: ds_read slot kt -> MFMA half 1 -> stage slot kt+3 -> MFMA
// half 2 -> counted vmcnt -> single barrier.
// T2: 16B-chunk XOR swizzle via pre-swizzled global source + swizzled read.
// T5: setprio(1) around MFMA clusters. T1: XCD-aware bijective block swizzle.

template<int BN, int HAS_BIAS, int HAS_RES, int RELU, int OUT_BF16, int ACCUM>
__global__ __launch_bounds__(512, 2) void mgemm3(
    const __bf16* __restrict__ A, const __bf16* __restrict__ Bm,
    void* __restrict__ Cv, const float* __restrict__ bias,
    const float* __restrict__ res,
    int M, int N, int K, int lda, int ldb, int nbx,
    size_t sA, size_t sB, size_t sC)
{
    constexpr int WTM = (BN == 256) ? 128 : 64;   // wave tile M
    constexpr int MI  = WTM / 16;                 // 8 or 4 A-frags
    constexpr int NSTG = (BN == 256) ? 4 : 3;     // gloads per stage per thread

    __shared__ __bf16 As[4][256 * 32];
    __shared__ __bf16 Bs[4][BN * 32];
    const int t = threadIdx.x;
    const int w = t >> 6, l = t & 63;
    const int lr = l & 15, lk = l >> 4;
    // T1: XCD swizzle (all grids are multiples of 8)
    const int nwg = gridDim.x;
    const int o = blockIdx.x;
    const int sid = (o & 7) * (nwg >> 3) + (o >> 3);
    const int bx = sid % nbx, by = sid / nbx;
    const int gm0 = by * 256, gn0 = bx * BN;
    const int wr = (BN == 256) ? (w >> 2) : (w >> 1);
    const int wc = (BN == 256) ? (w & 3) : (w & 1);
    const int z = blockIdx.y;
    A  += (size_t)z * sA;
    Bm += (size_t)z * sB;

    // staging geometry: wave w covers LDS rows [(w*2+j)*16, +16) of A (and of B
    // when BN==256; B is one 16-row chunk per wave when BN==128).
    const int srow16 = w * 2;
    const int lrow   = l >> 2;                    // row within 16-row block
    const int schunk = (l & 3) ^ ((l >> 3) & 3);  // swizzled source 16B chunk

    #define STAGE(WS_, kt_) do {                                               \
        const int kb_ = (kt_) << 5;                                            \
        _Pragma("unroll")                                                      \
        for (int j = 0; j < 2; ++j)                                            \
            gload_lds16(A + (size_t)(gm0 + (srow16 + j) * 16 + lrow) * lda     \
                          + kb_ + schunk * 8,                                  \
                        (char*)(&As[WS_][0]) + (srow16 + j) * 1024);           \
        if (BN == 256) {                                                       \
            _Pragma("unroll")                                                  \
            for (int j = 0; j < 2; ++j)                                        \
                gload_lds16(Bm + (size_t)(gn0 + (srow16 + j) * 16 + lrow) * ldb\
                              + kb_ + schunk * 8,                              \
                            (char*)(&Bs[WS_][0]) + (srow16 + j) * 1024);       \
        } else {                                                               \
            gload_lds16(Bm + (size_t)(gn0 + w * 16 + lrow) * ldb               \
                          + kb_ + schunk * 8,                                  \
                        (char*)(&Bs[WS_][0]) + w * 1024);                      \
        }                                                                      \
    } while (0)

    f32x4 acc[MI][4] = {};
    const int nkt = K >> 5;            // multiple of 4 for K in {1024,2048,4096}
    STAGE(0, 0); STAGE(1, 1); STAGE(2, 2);
    if constexpr (NSTG == 4) asm volatile("s_waitcnt vmcnt(8)" ::: "memory");
    else                     asm volatile("s_waitcnt vmcnt(6)" ::: "memory");
    __builtin_amdgcn_s_barrier();      // slot 0 resident for all waves

    const int swz = (lk ^ ((lr >> 1) & 3)) * 8;   // swizzled read chunk (elems)
    #pragma unroll 1
    for (int g = 0; g < nkt; g += 4) {
        #pragma unroll
        for (int i = 0; i < 4; ++i) {             // full unroll -> literal slots
            const int kt = g + i;
            bf16x8 a[MI], b[4];
            #pragma unroll
            for (int nj = 0; nj < 4; ++nj)
                b[nj] = *reinterpret_cast<const bf16x8*>(
                    &Bs[i][(wc * 64 + nj * 16 + lr) * 32 + swz]);
            #pragma unroll
            for (int mi = 0; mi < MI; ++mi)
                a[mi] = *reinterpret_cast<const bf16x8*>(
                    &As[i][(wr * WTM + mi * 16 + lr) * 32 + swz]);
            // MFMA half 1
            __builtin_amdgcn_s_setprio(1);
            #pragma unroll
            for (int mi = 0; mi < MI / 2; ++mi)
                #pragma unroll
                for (int nj = 0; nj < 4; ++nj)
                    acc[mi][nj] = __builtin_amdgcn_mfma_f32_16x16x32_bf16(
                        a[mi], b[nj], acc[mi][nj], 0, 0, 0);
            __builtin_amdgcn_s_setprio(0);
            // prefetch slot kt+3 between MFMA clusters
            if (kt + 3 < nkt) STAGE((i + 3) & 3, kt + 3);
            // MFMA half 2
            __builtin_amdgcn_s_setprio(1);
            #pragma unroll
            for (int mi = MI / 2; mi < MI; ++mi)
                #pragma unroll
                for (int nj = 0; nj < 4; ++nj)
                    acc[mi][nj] = __builtin_amdgcn_mfma_f32_16x16x32_bf16(
                        a[mi], b[nj], acc[mi][nj], 0, 0, 0);
            __builtin_amdgcn_s_setprio(0);
            // counted drain: guarantee slot kt+1 resident; keep rest in flight
            if (kt + 3 < nkt) {
                if (NSTG == 4) asm volatile("s_waitcnt vmcnt(8)" ::: "memory");
                else           asm volatile("s_waitcnt vmcnt(6)" ::: "memory");
                __builtin_amdgcn_s_barrier();
            } else if (kt + 2 < nkt) {
                if (NSTG == 4) asm volatile("s_waitcnt vmcnt(4)" ::: "memory");
                else           asm volatile("s_waitcnt vmcnt(3)" ::: "memory");
                __builtin_amdgcn_s_barrier();
            } else if (kt + 1 < nkt) {
                asm volatile("s_waitcnt vmcnt(0)" ::: "memory");
                __builtin_amdgcn_s_barrier();
            }
        }
    }
    #undef STAGE

    float*  Cf = (float*)Cv  + (size_t)z * sC;
    __bf16* Cb = (__bf16*)Cv + (size_t)z * sC;
    const float* rp = HAS_RES ? (res + (size_t)z * sC) : nullptr;
    #pragma unroll
    for (int mi = 0; mi < MI; ++mi) {
        int rbase = gm0 + wr * WTM + mi * 16 + lk * 4;
        #pragma unroll
        for (int nj = 0; nj < 4; ++nj) {
            int col = gn0 + wc * 64 + nj * 16 + lr;
            float bv = HAS_BIAS ? bias[col] : 0.0f;
            #pragma unroll
            for (int r = 0; r < 4; ++r) {
                size_t oo = (size_t)(rbase + r) * N + col;
                float val = acc[mi][nj][r] + bv;
                if (RELU) val = fmaxf(val, 0.0f);
                if (HAS_RES) val += rp[oo];
                if (OUT_BF16)    Cb[oo] = (__bf16)val;
                else if (ACCUM)  Cf[oo] += val;
                else             Cf[oo] = val;
            }
        }
    }
}

// ---------------- launch ----------------

extern "C" void kernel_launch(void* const* d_in, const int* in_sizes, int n_in,
                              void* d_out, int out_size, void* d_ws, size_t ws_size,
                              hipStream_t stream)
{
    (void)in_sizes; (void)n_in; (void)out_size; (void)ws_size;
    const int*   ids  = (const int*)d_in[0];
    const int*   occ  = (const int*)d_in[1];
    const int*   gen  = (const int*)d_in[2];
    const float* mask = (const float*)d_in[3];
    const float* tok  = (const float*)d_in[4];
    const float* pos  = (const float*)d_in[5];
    const float* oe   = (const float*)d_in[6];
    const float* ge   = (const float*)d_in[7];
    const float* pW   = (const float*)d_in[8];
    const float* pb   = (const float*)d_in[9];
    const float* lnw  = (const float*)d_in[10];
    const float* lnb  = (const float*)d_in[11];
    const float* w1   = (const float*)d_in[12];
    const float* b1   = (const float*)d_in[13];
    const float* w2   = (const float*)d_in[14];
    const float* b2   = (const float*)d_in[15];
    const float* oW   = (const float*)d_in[16];
    const float* ob   = (const float*)d_in[17];
    float* out = (float*)d_out;

    const size_t SD = (size_t)S_ * D_;
    const size_t SS = (size_t)S_ * S_;
    // Workspace total ~210 MB (proven safe in R4; 274 MB crashed in R3).
    char* wp = (char*)d_ws;
    float* x    = (float*)wp;  wp += (size_t)B_ * SD * 4;      // fp32 residual (64MB)
    float* pr   = (float*)wp;  wp += (size_t)B_ * D_ * 4;      // proj rows
    __bf16* n_bf  = (__bf16*)wp; wp += (size_t)B_ * SD * 2;    // LN out [B*S][D] (32MB)
    __bf16* n_bfT = (__bf16*)wp; wp += (size_t)B_ * SD * 2;    // [B][D][S] (32MB)
    __bf16* big   = (__bf16*)wp; wp += 2 * SS * 2;             // scores pair | FFN h (64MB)
    __bf16* w1t   = (__bf16*)wp; wp += (size_t)L_ * FF_ * D_ * 2;  // 8MB
    __bf16* w2t   = (__bf16*)wp; wp += (size_t)L_ * D_ * FF_ * 2;  // 8MB
    __bf16* owh   = (__bf16*)wp; wp += (size_t)V_ * D_ * 2;        // 1MB
    __bf16* owl   = (__bf16*)wp; wp += (size_t)V_ * D_ * 2;        // 1MB
    __bf16* x_hi  = n_bf;    // aliased: n_bf dead after final FFN1
    __bf16* x_lo  = n_bfT;   // aliased: n_bfT dead after final PV

    proj_kernel<<<B_, 256, 0, stream>>>(occ, gen, oe, ge, pW, pb, pr);
    embed_kernel<<<B_ * S_, 256, 0, stream>>>(ids, tok, pos, pr, x);

    for (int l = 0; l < L_; ++l) {
        tcast_f32<0><<<dim3(FF_ / 32, D_ / 32), 256, 0, stream>>>(
            w1 + (size_t)l * D_ * FF_, w1t + (size_t)l * FF_ * D_, nullptr, D_, FF_);
        tcast_f32<0><<<dim3(D_ / 32, FF_ / 32), 256, 0, stream>>>(
            w2 + (size_t)l * FF_ * D_, w2t + (size_t)l * D_ * FF_, nullptr, FF_, D_);
    }
    tcast_f32<1><<<dim3(V_ / 32, D_ / 32), 256, 0, stream>>>(oW, owh, owl, D_, V_);

    for (int l = 0; l < L_; ++l) {
        const float* w  = lnw + l * D_;
        const float* bb = lnb + l * D_;
        ln_kernel<<<B_ * S_, 256, 0, stream>>>(x, n_bf, w, bb);
        tcast_b16<<<dim3(D_ / 32, S_ / 32, B_), 256, 0, stream>>>(n_bf, n_bfT, S_, D_);
        for (int p = 0; p < 2; ++p) {            // batch pairs
            for (int q = 0; q < 2; ++q) {
                int b = 2 * p + q;
                // scores (bf16) = n_b @ n_b^T  (scale folded into softmax)
                mgemm3<256, 0, 0, 0, 1, 0><<<dim3((S_/256)*(S_/256), 1), 512, 0, stream>>>(
                    n_bf + b * SD, n_bf + b * SD, big + q * SS, nullptr, nullptr,
                    S_, S_, D_, D_, D_, S_ / 256, 0, 0, 0);
                softmax_b16<<<S_, 256, 0, stream>>>(big + q * SS, mask + (size_t)b * S_);
            }
            // x += probs @ n  for both batches of the pair (z = 2, BN=128 -> 256 blocks)
            mgemm3<128, 0, 1, 0, 0, 0><<<dim3((D_/128)*(S_/256), 2), 512, 0, stream>>>(
                big, n_bfT + (size_t)(2 * p) * SD, x + (size_t)(2 * p) * SD,
                nullptr, x + (size_t)(2 * p) * SD,
                S_, D_, S_, S_, S_, D_ / 128, SS, SD, SD);
        }
        ln_kernel<<<B_ * S_, 256, 0, stream>>>(x, n_bf, w, bb);
        // h = relu(na @ W1 + b1), all batches, bf16 out into big
        mgemm3<256, 1, 0, 1, 1, 0><<<dim3((FF_/256)*((B_*S_)/256), 1), 512, 0, stream>>>(
            n_bf, w1t + (size_t)l * FF_ * D_, big, b1 + l * FF_, nullptr,
            B_ * S_, FF_, D_, D_, D_, FF_ / 256, 0, 0, 0);
        // x += h @ W2 + b2
        mgemm3<256, 1, 1, 0, 0, 0><<<dim3((D_/256)*((B_*S_)/256), 1), 512, 0, stream>>>(
            big, w2t + (size_t)l * D_ * FF_, x, b2 + l * D_, x,
            B_ * S_, D_, FF_, FF_, FF_, D_ / 256, 0, 0, 0);
    }

    // out = x @ out_W + out_b, split-bf16 (hi*hi + hi*lo + lo*hi), BN=128 -> 256 blocks
    splitx_kernel<<<(int)((B_ * SD / 4 + 255) / 256), 256, 0, stream>>>(
        x, x_hi, x_lo, (long)(B_ * SD / 4));
    mgemm3<128, 1, 0, 0, 0, 0><<<dim3((V_/128)*((B_*S_)/256), 1), 512, 0, stream>>>(
        x_hi, owh, out, ob, nullptr, B_ * S_, V_, D_, D_, D_, V_ / 128, 0, 0, 0);
    mgemm3<128, 0, 0, 0, 0, 1><<<dim3((V_/128)*((B_*S_)/256), 1), 512, 0, stream>>>(
        x_hi, owl, out, nullptr, nullptr, B_ * S_, V_, D_, D_, D_, V_ / 128, 0, 0, 0);
    mgemm3<128, 0, 0, 0, 0, 1><<<dim3((V_/128)*((B_*S_)/256), 1), 512, 0, stream>>>(
        x_lo, owh, out, nullptr, nullptr, B_ * S_, V_, D_, D_, D_, V_ / 128, 0, 0, 0);
}